// Round 1
// baseline (409.016 us; speedup 1.0000x reference)
//
#include <hip/hip_runtime.h>
#include <hip/hip_bf16.h>

// PointerNet: out[b][k] = sum_c C_k[b,c] * sigmoid(WP[b,c]+WC_k[b,c]+Gb[c]) * (WPo[b,c]+Ob[c])
//   WP,WPo = P @ [GateWeight_P | OutWeight]  (one GEMM, M=8192,N=2048,K=1024)
//   WC_k   = C_k @ GateWeight_C              (one GEMM, M=32768,N=1024,K=1024)
// All GEMMs in bf16 MFMA (16x16x32), m97-style 128x128 tile + global_load_lds.

#define B_  8192
#define PD_ 1024
#define CD_ 1024

typedef unsigned short ushort_t;
typedef __attribute__((ext_vector_type(8))) short    short8;   // 8 bf16 = 4 VGPRs (MFMA A/B frag)
typedef __attribute__((ext_vector_type(8))) unsigned short ushort8;
typedef __attribute__((ext_vector_type(4))) float    floatx4;

__device__ __forceinline__ float bf2f(unsigned short u) {
    return __uint_as_float(((unsigned)u) << 16);
}
__device__ __forceinline__ unsigned short f2bf(float f) {
    unsigned u = __float_as_uint(f);
    unsigned r = u + 0x7FFFu + ((u >> 16) & 1u);   // RNE
    return (unsigned short)(r >> 16);
}

// ---------------- cast fp32 -> bf16 (4 elems / thread) ----------------
__global__ __launch_bounds__(256) void cast_kernel(const float* __restrict__ src,
                                                   ushort_t* __restrict__ dst, int n4) {
    int i = blockIdx.x * 256 + threadIdx.x;
    if (i >= n4) return;
    float4 v = ((const float4*)src)[i];
    ushort4 o;
    o.x = f2bf(v.x); o.y = f2bf(v.y); o.z = f2bf(v.z); o.w = f2bf(v.w);
    ((ushort4*)dst)[i] = o;
}

// ---------------- transpose + cast: src[R][C] fp32 -> dst[C][R] bf16 ----------------
__global__ __launch_bounds__(256) void transpose_cast(const float* __restrict__ src,
                                                      ushort_t* __restrict__ dst,
                                                      int R, int C) {
    __shared__ float tile[32][33];
    int c0 = blockIdx.x * 32, r0 = blockIdx.y * 32;
    int x = threadIdx.x, y = threadIdx.y;
    for (int i = y; i < 32; i += 8)
        tile[i][x] = src[(size_t)(r0 + i) * C + c0 + x];
    __syncthreads();
    for (int i = y; i < 32; i += 8)
        dst[(size_t)(c0 + i) * R + r0 + x] = f2bf(tile[x][i]);
}

// ---------------- bf16 GEMM, A[M,K] row-major, Bt[N,K] row-major, C[M,N] bf16 ----------------
__device__ __forceinline__ void gl_lds16(const void* g, void* l) {
    __builtin_amdgcn_global_load_lds((const __attribute__((address_space(1))) void*)g,
                                     (__attribute__((address_space(3))) void*)l, 16, 0, 0);
}

__global__ __launch_bounds__(256) void gemm_bt(const ushort_t* __restrict__ A,
                                               const ushort_t* __restrict__ Bt,
                                               ushort_t* __restrict__ C,
                                               int M, int N, int K) {
    __shared__ ushort_t lA[128 * 32];   // 8 KB
    __shared__ ushort_t lB[128 * 32];   // 8 KB
    const int t    = threadIdx.x;
    const int wave = t >> 6, lane = t & 63;
    const int quad = lane >> 4, l16 = lane & 15;
    const int wm   = wave >> 1, wn  = wave & 1;
    const int tileM = blockIdx.y * 128, tileN = blockIdx.x * 128;

    // staging: 8 KB tile = 8 chunks of 1 KB; wave w stages chunks {2w, 2w+1}
    // chunk c: rows c*16..c*16+15 of the tile (row = 32 bf16 = 64 B)
    const int ch0 = wave * 2;
    const int sr0 = ch0 * 16 + (lane >> 2);        // tile-row for chunk ch0
    const int sc  = (lane & 3) * 8;                // k-offset (elements)
    const int lo0 = ch0 * 512 + lane * 8;          // LDS element offset (base + lane*16B)

    const ushort_t* Ag0 = A  + (size_t)(tileM + sr0)      * K + sc;
    const ushort_t* Ag1 = A  + (size_t)(tileM + sr0 + 16) * K + sc;
    const ushort_t* Bg0 = Bt + (size_t)(tileN + sr0)      * K + sc;
    const ushort_t* Bg1 = Bt + (size_t)(tileN + sr0 + 16) * K + sc;

    floatx4 acc[4][4];
#pragma unroll
    for (int i = 0; i < 4; i++)
#pragma unroll
        for (int j = 0; j < 4; j++) acc[i][j] = (floatx4)0.f;

    for (int k0 = 0; k0 < K; k0 += 32) {
        gl_lds16(Ag0 + k0, &lA[lo0]);
        gl_lds16(Ag1 + k0, &lA[lo0 + 512]);
        gl_lds16(Bg0 + k0, &lB[lo0]);
        gl_lds16(Bg1 + k0, &lB[lo0 + 512]);
        __syncthreads();   // drains vmcnt(0) then barrier

        short8 af[4], bfr[4];
#pragma unroll
        for (int mi = 0; mi < 4; mi++)
            af[mi] = *(const short8*)&lA[(wm * 64 + mi * 16 + l16) * 32 + quad * 8];
#pragma unroll
        for (int ni = 0; ni < 4; ni++)
            bfr[ni] = *(const short8*)&lB[(wn * 64 + ni * 16 + l16) * 32 + quad * 8];
#pragma unroll
        for (int mi = 0; mi < 4; mi++)
#pragma unroll
            for (int ni = 0; ni < 4; ni++)
                acc[mi][ni] = __builtin_amdgcn_mfma_f32_16x16x32_bf16(
                    af[mi], bfr[ni], acc[mi][ni], 0, 0, 0);
        __syncthreads();
    }

    // C/D layout: col = lane&15, row = quad*4 + reg  [verified m89/m91]
#pragma unroll
    for (int mi = 0; mi < 4; mi++)
#pragma unroll
        for (int ni = 0; ni < 4; ni++)
#pragma unroll
            for (int r = 0; r < 4; r++) {
                int row = tileM + wm * 64 + mi * 16 + quad * 4 + r;
                int col = tileN + wn * 64 + ni * 16 + l16;
                C[(size_t)row * N + col] = f2bf(acc[mi][ni][r]);
            }
}

// ---------------- epilogue: one wave per batch row b ----------------
__global__ __launch_bounds__(256) void epilogue(const ushort_t* __restrict__ WPcat, // [B][2048]
                                                const ushort_t* __restrict__ WC,    // [4*B][1024]
                                                const ushort_t* __restrict__ Call,  // [4*B][1024]
                                                const float* __restrict__ Gb,       // [1024]
                                                const float* __restrict__ Ob,       // [1024]
                                                float* __restrict__ out) {          // [B][4]
    const int wave = threadIdx.x >> 6, lane = threadIdx.x & 63;
    const int b = blockIdx.x * 4 + wave;
    float acc[4] = {0.f, 0.f, 0.f, 0.f};

#pragma unroll
    for (int it = 0; it < 2; it++) {
        const int c = it * 512 + lane * 8;
        ushort8 wp  = *(const ushort8*)&WPcat[(size_t)b * 2048 + c];
        ushort8 wpo = *(const ushort8*)&WPcat[(size_t)b * 2048 + 1024 + c];
        floatx4 g0 = *(const floatx4*)&Gb[c];
        floatx4 g1 = *(const floatx4*)&Gb[c + 4];
        floatx4 o0 = *(const floatx4*)&Ob[c];
        floatx4 o1 = *(const floatx4*)&Ob[c + 4];
        float gb[8], ob[8];
#pragma unroll
        for (int j = 0; j < 4; j++) { gb[j] = g0[j]; gb[4 + j] = g1[j]; ob[j] = o0[j]; ob[4 + j] = o1[j]; }

        float po[8], wpf[8];
#pragma unroll
        for (int j = 0; j < 8; j++) {
            wpf[j] = bf2f(wp[j]);
            po[j]  = bf2f(wpo[j]) + ob[j];
        }
#pragma unroll
        for (int k = 0; k < 4; k++) {
            size_t off = ((size_t)k * B_ + b) * 1024 + c;
            ushort8 cv = *(const ushort8*)&Call[off];
            ushort8 wc = *(const ushort8*)&WC[off];
            float s = 0.f;
#pragma unroll
            for (int j = 0; j < 8; j++) {
                float x = wpf[j] + bf2f(wc[j]) + gb[j];
                float g = 1.f / (1.f + __expf(-x));
                s += bf2f(cv[j]) * g * po[j];
            }
            acc[k] += s;
        }
    }
#pragma unroll
    for (int k = 0; k < 4; k++) {
#pragma unroll
        for (int off = 32; off > 0; off >>= 1)
            acc[k] += __shfl_down(acc[k], off);
    }
    if (lane == 0) {
        out[(size_t)b * 4 + 0] = acc[0];
        out[(size_t)b * 4 + 1] = acc[1];
        out[(size_t)b * 4 + 2] = acc[2];
        out[(size_t)b * 4 + 3] = acc[3];
    }
}

extern "C" void kernel_launch(void* const* d_in, const int* in_sizes, int n_in,
                              void* d_out, int out_size, void* d_ws, size_t ws_size,
                              hipStream_t stream) {
    (void)in_sizes; (void)n_in; (void)out_size; (void)ws_size;
    const float* P   = (const float*)d_in[0];
    const float* C1  = (const float*)d_in[1];
    const float* C2  = (const float*)d_in[2];
    const float* C3  = (const float*)d_in[3];
    const float* C4  = (const float*)d_in[4];
    const float* GWP = (const float*)d_in[5];
    const float* GWC = (const float*)d_in[6];
    const float* Gb  = (const float*)d_in[7];
    const float* OW  = (const float*)d_in[8];
    const float* Ob  = (const float*)d_in[9];
    float* out = (float*)d_out;

    // workspace layout (bf16 everywhere): 182 MiB total
    char* ws = (char*)d_ws;
    ushort_t* Pb    = (ushort_t*)(ws);                      // 16 MiB  P bf16 [8192][1024]
    ushort_t* Call  = (ushort_t*)(ws + (16u  << 20));       // 64 MiB  [4][8192][1024]
    ushort_t* Wcat  = (ushort_t*)(ws + (80u  << 20));       //  4 MiB  [2048][1024] = [GWP^T; OW^T]
    ushort_t* GWCt  = (ushort_t*)(ws + (84u  << 20));       //  2 MiB  [1024][1024] = GWC^T
    ushort_t* WPcat = (ushort_t*)(ws + (86u  << 20));       // 32 MiB  [8192][2048]
    ushort_t* WC    = (ushort_t*)(ws + (118u << 20));       // 64 MiB  [4*8192][1024]

    const int n4 = B_ * PD_ / 4;            // 2,097,152 quads per matrix
    const int cgrid = n4 / 256;             // 8192 blocks

    cast_kernel<<<cgrid, 256, 0, stream>>>(P,  Pb, n4);
    cast_kernel<<<cgrid, 256, 0, stream>>>(C1, Call + (size_t)0 * B_ * CD_, n4);
    cast_kernel<<<cgrid, 256, 0, stream>>>(C2, Call + (size_t)1 * B_ * CD_, n4);
    cast_kernel<<<cgrid, 256, 0, stream>>>(C3, Call + (size_t)2 * B_ * CD_, n4);
    cast_kernel<<<cgrid, 256, 0, stream>>>(C4, Call + (size_t)3 * B_ * CD_, n4);

    transpose_cast<<<dim3(32, 32), dim3(32, 8), 0, stream>>>(GWP, Wcat,               1024, 1024);
    transpose_cast<<<dim3(32, 32), dim3(32, 8), 0, stream>>>(OW,  Wcat + 1024 * 1024, 1024, 1024);
    transpose_cast<<<dim3(32, 32), dim3(32, 8), 0, stream>>>(GWC, GWCt,               1024, 1024);

    // WPcat = Pb @ Wcat^T  (M=8192, N=2048, K=1024)
    gemm_bt<<<dim3(16, 64), 256, 0, stream>>>(Pb, Wcat, WPcat, B_, 2048, 1024);
    // WC = Call @ GWCt^T   (M=32768, N=1024, K=1024)
    gemm_bt<<<dim3(8, 256), 256, 0, stream>>>(Call, GWCt, WC, 4 * B_, 1024, 1024);

    epilogue<<<B_ / 4, 256, 0, stream>>>(WPcat, WC, Call, Gb, Ob, out);
}

// Round 2
// 361.556 us; speedup vs baseline: 1.1313x; 1.1313x over previous
//
#include <hip/hip_runtime.h>
#include <hip/hip_bf16.h>

// PointerNet: out[b][k] = sum_c C_k[b,c] * sigmoid(WP[b,c]+WC_k[b,c]+Gb[c]) * (WPo[b,c]+Ob[c])
//   WP,WPo = P @ [GateWeight_P | OutWeight]  (GEMM seg A: M=8192,N=2048,K=1024)
//   WC_k   = C_k @ GateWeight_C              (GEMM seg B: M=32768,N=1024,K=1024)
// R2: XOR-swizzled LDS (kills 8-way ds_read_b128 bank conflicts; global coalescing
//     unchanged at 16x64B segments), both GEMMs in one 3072-block launch,
//     5 casts fused into 1 kernel, 3 transposes fused into 1 kernel.

#define B_  8192
#define PD_ 1024
#define CD_ 1024

typedef unsigned short ushort_t;
typedef __attribute__((ext_vector_type(8))) short    short8;   // 8 bf16 = 4 VGPRs (MFMA A/B frag)
typedef __attribute__((ext_vector_type(8))) unsigned short ushort8;
typedef __attribute__((ext_vector_type(4))) float    floatx4;

__device__ __forceinline__ float bf2f(unsigned short u) {
    return __uint_as_float(((unsigned)u) << 16);
}
__device__ __forceinline__ unsigned short f2bf(float f) {
    unsigned u = __float_as_uint(f);
    unsigned r = u + 0x7FFFu + ((u >> 16) & 1u);   // RNE
    return (unsigned short)(r >> 16);
}

// ---------------- fused cast fp32 -> bf16: P, C1..C4 in one launch ----------------
// 8192 blocks per segment x 5 segments; 4 elems/thread.
__global__ __launch_bounds__(256) void cast5_kernel(const float* __restrict__ P,
                                                    const float* __restrict__ C1,
                                                    const float* __restrict__ C2,
                                                    const float* __restrict__ C3,
                                                    const float* __restrict__ C4,
                                                    ushort_t* __restrict__ Pb,
                                                    ushort_t* __restrict__ Call) {
    const int seg = blockIdx.x >> 13;                 // 8192 blocks / segment
    const int i   = (blockIdx.x & 8191) * 256 + threadIdx.x;
    const float* src;
    ushort_t* dst;
    switch (seg) {
        case 0: src = P;  dst = Pb; break;
        case 1: src = C1; dst = Call; break;
        case 2: src = C2; dst = Call + (size_t)1 * B_ * CD_; break;
        case 3: src = C3; dst = Call + (size_t)2 * B_ * CD_; break;
        default: src = C4; dst = Call + (size_t)3 * B_ * CD_; break;
    }
    float4 v = ((const float4*)src)[i];
    ushort4 o;
    o.x = f2bf(v.x); o.y = f2bf(v.y); o.z = f2bf(v.z); o.w = f2bf(v.w);
    ((ushort4*)dst)[i] = o;
}

// ---------------- fused transpose + cast: 3 weight matrices (1024x1024) ----------------
__global__ __launch_bounds__(256) void transpose3(const float* __restrict__ GWP,
                                                  const float* __restrict__ OW,
                                                  const float* __restrict__ GWC,
                                                  ushort_t* __restrict__ Wcat,
                                                  ushort_t* __restrict__ GWCt) {
    __shared__ float tile[32][33];
    const float* src;
    ushort_t* dst;
    switch (blockIdx.z) {
        case 0: src = GWP; dst = Wcat; break;
        case 1: src = OW;  dst = Wcat + 1024 * 1024; break;
        default: src = GWC; dst = GWCt; break;
    }
    const int R = 1024, C = 1024;
    int c0 = blockIdx.x * 32, r0 = blockIdx.y * 32;
    int x = threadIdx.x, y = threadIdx.y;
    for (int i = y; i < 32; i += 8)
        tile[i][x] = src[(size_t)(r0 + i) * C + c0 + x];
    __syncthreads();
    for (int i = y; i < 32; i += 8)
        dst[(size_t)(c0 + i) * R + r0 + x] = f2bf(tile[x][i]);
}

// ---------------- bf16 GEMM, both segments in one launch ----------------
// A[M,K] row-major, Bt[N,K] row-major, C[M,N] bf16. K=1024 fixed.
// LDS tile layout (per 1KB chunk = 16 rows x 32 k): staging lane L writes slot L
// (16B units). Lane L sources global (row = L>>2, kchunk = (L&3) ^ ((L>>4)&3)).
// => element (r16, kchunk q) lives at slot r16*4 + (q ^ (r16>>2)); fragment reads
// alias banks only 2-way (free, m136), vs 8-way in the unswizzled layout.
__device__ __forceinline__ void gl_lds16(const void* g, void* l) {
    __builtin_amdgcn_global_load_lds((const __attribute__((address_space(1))) void*)g,
                                     (__attribute__((address_space(3))) void*)l, 16, 0, 0);
}

__global__ __launch_bounds__(256) void gemm_fused(const ushort_t* __restrict__ Pb,
                                                  const ushort_t* __restrict__ Wcat,
                                                  ushort_t* __restrict__ WPcat,
                                                  const ushort_t* __restrict__ Call,
                                                  const ushort_t* __restrict__ GWCt,
                                                  ushort_t* __restrict__ WC) {
    __shared__ ushort_t lA[128 * 32];   // 8 KB
    __shared__ ushort_t lB[128 * 32];   // 8 KB
    const int K = 1024;

    const ushort_t *A, *Bt;
    ushort_t* Cc;
    int N, tileM, tileN;
    const int bid = blockIdx.x;
    if (bid < 1024) {            // seg A: M=8192, N=2048 (grid 16 x 64)
        A = Pb; Bt = Wcat; Cc = WPcat; N = 2048;
        tileN = (bid & 15) * 128; tileM = (bid >> 4) * 128;
    } else {                     // seg B: M=32768, N=1024 (grid 8 x 256)
        const int b2 = bid - 1024;
        A = Call; Bt = GWCt; Cc = WC; N = 1024;
        tileN = (b2 & 7) * 128; tileM = (b2 >> 3) * 128;
    }

    const int t    = threadIdx.x;
    const int wave = t >> 6, lane = t & 63;
    const int quad = lane >> 4, l16 = lane & 15;
    const int wm   = wave >> 1, wn  = wave & 1;

    // staging: wave w stages chunks {2w, 2w+1}
    const int ch0  = wave * 2;
    const int srow = lane >> 2;                          // 0..15 within chunk
    const int skc  = (lane & 3) ^ ((lane >> 4) & 3);     // XOR swizzle
    const int sc   = skc * 8;                            // k element offset
    const int lo0  = ch0 * 512 + lane * 8;               // LDS element offset

    const ushort_t* Ag0 = A  + (size_t)(tileM + ch0 * 16 + srow)      * K + sc;
    const ushort_t* Ag1 = A  + (size_t)(tileM + ch0 * 16 + srow + 16) * K + sc;
    const ushort_t* Bg0 = Bt + (size_t)(tileN + ch0 * 16 + srow)      * K + sc;
    const ushort_t* Bg1 = Bt + (size_t)(tileN + ch0 * 16 + srow + 16) * K + sc;

    // fragment read offsets (elements): slot = l16*4 + (quad ^ (l16>>2)), 8 elems/slot
    const int fro = (l16 * 4 + (quad ^ (l16 >> 2))) * 8;

    floatx4 acc[4][4];
#pragma unroll
    for (int i = 0; i < 4; i++)
#pragma unroll
        for (int j = 0; j < 4; j++) acc[i][j] = (floatx4)0.f;

    for (int k0 = 0; k0 < K; k0 += 32) {
        gl_lds16(Ag0 + k0, &lA[lo0]);
        gl_lds16(Ag1 + k0, &lA[lo0 + 512]);
        gl_lds16(Bg0 + k0, &lB[lo0]);
        gl_lds16(Bg1 + k0, &lB[lo0 + 512]);
        __syncthreads();

        short8 af[4], bfr[4];
#pragma unroll
        for (int mi = 0; mi < 4; mi++)
            af[mi] = *(const short8*)&lA[(wm * 4 + mi) * 512 + fro];
#pragma unroll
        for (int ni = 0; ni < 4; ni++)
            bfr[ni] = *(const short8*)&lB[(wn * 4 + ni) * 512 + fro];
#pragma unroll
        for (int mi = 0; mi < 4; mi++)
#pragma unroll
            for (int ni = 0; ni < 4; ni++)
                acc[mi][ni] = __builtin_amdgcn_mfma_f32_16x16x32_bf16(
                    af[mi], bfr[ni], acc[mi][ni], 0, 0, 0);
        __syncthreads();
    }

    // C/D layout: col = lane&15, row = quad*4 + reg  [verified m89/m91]
#pragma unroll
    for (int mi = 0; mi < 4; mi++)
#pragma unroll
        for (int ni = 0; ni < 4; ni++)
#pragma unroll
            for (int r = 0; r < 4; r++) {
                int row = tileM + wm * 64 + mi * 16 + quad * 4 + r;
                int col = tileN + wn * 64 + ni * 16 + l16;
                Cc[(size_t)row * N + col] = f2bf(acc[mi][ni][r]);
            }
}

// ---------------- epilogue: one wave per batch row b ----------------
__global__ __launch_bounds__(256) void epilogue(const ushort_t* __restrict__ WPcat, // [B][2048]
                                                const ushort_t* __restrict__ WC,    // [4*B][1024]
                                                const ushort_t* __restrict__ Call,  // [4*B][1024]
                                                const float* __restrict__ Gb,       // [1024]
                                                const float* __restrict__ Ob,       // [1024]
                                                float* __restrict__ out) {          // [B][4]
    const int wave = threadIdx.x >> 6, lane = threadIdx.x & 63;
    const int b = blockIdx.x * 4 + wave;
    float acc[4] = {0.f, 0.f, 0.f, 0.f};

#pragma unroll
    for (int it = 0; it < 2; it++) {
        const int c = it * 512 + lane * 8;
        ushort8 wp  = *(const ushort8*)&WPcat[(size_t)b * 2048 + c];
        ushort8 wpo = *(const ushort8*)&WPcat[(size_t)b * 2048 + 1024 + c];
        floatx4 g0 = *(const floatx4*)&Gb[c];
        floatx4 g1 = *(const floatx4*)&Gb[c + 4];
        floatx4 o0 = *(const floatx4*)&Ob[c];
        floatx4 o1 = *(const floatx4*)&Ob[c + 4];
        float gb[8], ob[8];
#pragma unroll
        for (int j = 0; j < 4; j++) { gb[j] = g0[j]; gb[4 + j] = g1[j]; ob[j] = o0[j]; ob[4 + j] = o1[j]; }

        float po[8], wpf[8];
#pragma unroll
        for (int j = 0; j < 8; j++) {
            wpf[j] = bf2f(wp[j]);
            po[j]  = bf2f(wpo[j]) + ob[j];
        }
#pragma unroll
        for (int k = 0; k < 4; k++) {
            size_t off = ((size_t)k * B_ + b) * 1024 + c;
            ushort8 cv = *(const ushort8*)&Call[off];
            ushort8 wc = *(const ushort8*)&WC[off];
            float s = 0.f;
#pragma unroll
            for (int j = 0; j < 8; j++) {
                float x = wpf[j] + bf2f(wc[j]) + gb[j];
                float g = 1.f / (1.f + __expf(-x));
                s += bf2f(cv[j]) * g * po[j];
            }
            acc[k] += s;
        }
    }
#pragma unroll
    for (int k = 0; k < 4; k++) {
#pragma unroll
        for (int off = 32; off > 0; off >>= 1)
            acc[k] += __shfl_down(acc[k], off);
    }
    if (lane == 0) {
        out[(size_t)b * 4 + 0] = acc[0];
        out[(size_t)b * 4 + 1] = acc[1];
        out[(size_t)b * 4 + 2] = acc[2];
        out[(size_t)b * 4 + 3] = acc[3];
    }
}

extern "C" void kernel_launch(void* const* d_in, const int* in_sizes, int n_in,
                              void* d_out, int out_size, void* d_ws, size_t ws_size,
                              hipStream_t stream) {
    (void)in_sizes; (void)n_in; (void)out_size; (void)ws_size;
    const float* P   = (const float*)d_in[0];
    const float* C1  = (const float*)d_in[1];
    const float* C2  = (const float*)d_in[2];
    const float* C3  = (const float*)d_in[3];
    const float* C4  = (const float*)d_in[4];
    const float* GWP = (const float*)d_in[5];
    const float* GWC = (const float*)d_in[6];
    const float* Gb  = (const float*)d_in[7];
    const float* OW  = (const float*)d_in[8];
    const float* Ob  = (const float*)d_in[9];
    float* out = (float*)d_out;

    // workspace layout (bf16 everywhere): 182 MiB total
    char* ws = (char*)d_ws;
    ushort_t* Pb    = (ushort_t*)(ws);                      // 16 MiB  P bf16 [8192][1024]
    ushort_t* Call  = (ushort_t*)(ws + (16u  << 20));       // 64 MiB  [4][8192][1024]
    ushort_t* Wcat  = (ushort_t*)(ws + (80u  << 20));       //  4 MiB  [2048][1024] = [GWP^T; OW^T]
    ushort_t* GWCt  = (ushort_t*)(ws + (84u  << 20));       //  2 MiB  [1024][1024] = GWC^T
    ushort_t* WPcat = (ushort_t*)(ws + (86u  << 20));       // 32 MiB  [8192][2048]
    ushort_t* WC    = (ushort_t*)(ws + (118u << 20));       // 64 MiB  [4*8192][1024]

    cast5_kernel<<<5 * 8192, 256, 0, stream>>>(P, C1, C2, C3, C4, Pb, Call);
    transpose3<<<dim3(32, 32, 3), dim3(32, 8), 0, stream>>>(GWP, OW, GWC, Wcat, GWCt);

    // seg A: WPcat = Pb @ Wcat^T (1024 blocks) ; seg B: WC = Call @ GWCt^T (2048 blocks)
    gemm_fused<<<3072, 256, 0, stream>>>(Pb, Wcat, WPcat, Call, GWCt, WC);

    epilogue<<<B_ / 4, 256, 0, stream>>>(WPcat, WC, Call, Gb, Ob, out);
}